// Round 6
// baseline (566.103 us; speedup 1.0000x reference)
//
#include <hip/hip_runtime.h>
#include <hip/hip_bf16.h>

#define N_NODES 100000
#define D 64
#define BSHIFT 8
#define NB 391            // ceil(100000 / 256) buckets of 256 nodes
#define CHUNK 8192
#define SCAN_BLK 1024
#define RSTRIDE 65        // LDS row stride (floats): odd -> rows spread across banks

// ---------- A: per-(chunk,bucket) histogram via LDS atomics ----------
__global__ void histA(const int* __restrict__ dst, int* __restrict__ counts,
                      int nchunk, int n_edges) {
    __shared__ int h[NB];
    for (int i = threadIdx.x; i < NB; i += blockDim.x) h[i] = 0;
    __syncthreads();
    int c = blockIdx.x;
    int start = c * CHUNK, end = min(start + CHUNK, n_edges);
    for (int e = start + threadIdx.x; e < end; e += blockDim.x)
        atomicAdd(&h[dst[e] >> BSHIFT], 1);
    __syncthreads();
    for (int b = threadIdx.x; b < NB; b += blockDim.x)
        counts[b * nchunk + c] = h[b];   // bucket-major so scan order = final order
}

// ---------- B: 3-level exclusive scan ----------
__global__ void bsum_kernel(const int* __restrict__ counts, int* __restrict__ bsums,
                            int n) {
    __shared__ int s[SCAN_BLK];
    int i = blockIdx.x * SCAN_BLK + threadIdx.x;
    s[threadIdx.x] = (i < n) ? counts[i] : 0;
    __syncthreads();
    for (int off = SCAN_BLK / 2; off > 0; off >>= 1) {
        if (threadIdx.x < off) s[threadIdx.x] += s[threadIdx.x + off];
        __syncthreads();
    }
    if (threadIdx.x == 0) bsums[blockIdx.x] = s[0];
}
__global__ void bscan_kernel(int* __restrict__ bsums, int nb) {
    __shared__ int s[SCAN_BLK];
    int tid = threadIdx.x;
    s[tid] = (tid < nb) ? bsums[tid] : 0;
    __syncthreads();
    for (int off = 1; off < SCAN_BLK; off <<= 1) {
        int t = (tid >= off) ? s[tid - off] : 0;
        __syncthreads();
        s[tid] += t;
        __syncthreads();
    }
    if (tid < nb) bsums[tid] = (tid > 0) ? s[tid - 1] : 0;
}
__global__ void offs_kernel(const int* __restrict__ counts, const int* __restrict__ bsums,
                            int* __restrict__ offsets, int n) {
    __shared__ int s[SCAN_BLK];
    int tid = threadIdx.x;
    int i = blockIdx.x * SCAN_BLK + tid;
    int v = (i < n) ? counts[i] : 0;
    s[tid] = v;
    __syncthreads();
    for (int off = 1; off < SCAN_BLK; off <<= 1) {
        int t = (tid >= off) ? s[tid - off] : 0;
        __syncthreads();
        s[tid] += t;
        __syncthreads();
    }
    if (i < n) offsets[i] = s[tid] - v + bsums[blockIdx.x];
}

// ---------- C: bucket-sorted scatter via LDS cursors ----------
__global__ void scatterC(const int* __restrict__ src, const int* __restrict__ dst,
                         const int* __restrict__ base, unsigned* __restrict__ sorted,
                         int nchunk, int n_edges) {
    __shared__ int cur[NB];
    int c = blockIdx.x;
    for (int b = threadIdx.x; b < NB; b += blockDim.x) cur[b] = base[b * nchunk + c];
    __syncthreads();
    int start = c * CHUNK, end = min(start + CHUNK, n_edges);
    for (int e = start + threadIdx.x; e < end; e += blockDim.x) {
        int d = dst[e];
        int b = d >> BSHIFT;
        int r = atomicAdd(&cur[b], 1);
        sorted[r] = ((unsigned)(d & 255) << 17) | (unsigned)src[e];  // src<2^17
    }
}

// ---------- D: per-bucket LDS accumulation, 16 lanes x float4 per edge ----------
__global__ void gatherD(const float* __restrict__ feat, const int* __restrict__ base,
                        const unsigned* __restrict__ sorted, float* __restrict__ out,
                        int nchunk, int n_edges) {
    extern __shared__ float smem[];                 // 256*RSTRIDE floats + 256 ints
    int* degl = (int*)(smem + 256 * RSTRIDE);
    int b = blockIdx.x;
    for (int i = threadIdx.x; i < 256 * RSTRIDE; i += 1024) smem[i] = 0.0f;
    for (int i = threadIdx.x; i < 256; i += 1024) degl[i] = 0;
    __syncthreads();

    int start = base[b * nchunk];
    int end = (b + 1 < NB) ? base[(b + 1) * nchunk] : n_edges;
    int group = threadIdx.x >> 4;                   // 0..63: edge slot within iter
    int gl = threadIdx.x & 15;                      // column group (float4)

    for (int e = start + group; e < end; e += 64) {
        unsigned p = sorted[e];
        int s = p & 0x1FFFF;
        int dl = (p >> 17) & 255;
        const float4 v = *reinterpret_cast<const float4*>(&feat[(size_t)s * D + gl * 4]);
        float* row = &smem[dl * RSTRIDE + gl * 4];
        atomicAdd(&row[0], v.x);
        atomicAdd(&row[1], v.y);
        atomicAdd(&row[2], v.z);
        atomicAdd(&row[3], v.w);
        if (gl == 0) atomicAdd(&degl[dl], 1);
    }
    __syncthreads();

    int node0 = b << BSHIFT;
    #pragma unroll
    for (int k = 0; k < 4; k++) {
        int idx = threadIdx.x + k * 1024;           // 256 nodes x 16 float4 slots
        int n = idx >> 4, q = idx & 15;
        int g = node0 + n;
        if (g < N_NODES) {
            int dg = degl[n];
            float inv = (dg > 0) ? 1.0f / (float)dg : 0.0f;
            float4 o;
            o.x = smem[n * RSTRIDE + q * 4 + 0] * inv;
            o.y = smem[n * RSTRIDE + q * 4 + 1] * inv;
            o.z = smem[n * RSTRIDE + q * 4 + 2] * inv;
            o.w = smem[n * RSTRIDE + q * 4 + 3] * inv;
            *reinterpret_cast<float4*>(&out[(size_t)g * D + q * 4]) = o;
        }
    }
}

// ---------- fallback (atomic scatter) if ws too small ----------
__global__ void gcn_scatter(const float* __restrict__ feat, const int* __restrict__ src,
                            const int* __restrict__ dst, float* __restrict__ out,
                            float* __restrict__ deg, int n_edges) {
    long long gtid = (long long)blockIdx.x * blockDim.x + threadIdx.x;
    int edge = (int)(gtid >> 6);
    int lane = threadIdx.x & 63;
    if (edge >= n_edges) return;
    atomicAdd(&out[(long long)dst[edge] * D + lane],
              feat[(long long)src[edge] * D + lane]);
    if (lane == 0) atomicAdd(&deg[dst[edge]], 1.0f);
}
__global__ void gcn_finalize(float* __restrict__ out, const float* __restrict__ deg,
                             int total) {
    int i = blockIdx.x * blockDim.x + threadIdx.x;
    if (i >= total) return;
    float dg = deg[i >> 6];
    out[i] = (dg > 0.0f) ? out[i] / dg : 0.0f;
}

extern "C" void kernel_launch(void* const* d_in, const int* in_sizes, int n_in,
                              void* d_out, int out_size, void* d_ws, size_t ws_size,
                              hipStream_t stream) {
    const float* feat = (const float*)d_in[0];
    const int* src = (const int*)d_in[1];
    const int* dst = (const int*)d_in[2];
    float* out = (float*)d_out;
    int n_edges = in_sizes[1];

    int nchunk = (n_edges + CHUNK - 1) / CHUNK;
    int ncounts = NB * nchunk;
    size_t need = ((size_t)ncounts * 2 + SCAN_BLK) * sizeof(int)
                + (size_t)n_edges * sizeof(unsigned);
    if (ws_size < need) {
        float* deg = (float*)d_ws;
        int total = N_NODES * D;
        hipMemsetAsync(out, 0, (size_t)total * sizeof(float), stream);
        hipMemsetAsync(deg, 0, (size_t)N_NODES * sizeof(float), stream);
        long long threads = (long long)n_edges * 64;
        int grid = (int)((threads + 255) / 256);
        gcn_scatter<<<grid, 256, 0, stream>>>(feat, src, dst, out, deg, n_edges);
        gcn_finalize<<<(total + 255) / 256, 256, 0, stream>>>(out, deg, total);
        return;
    }

    int* counts = (int*)d_ws;                    // ncounts
    int* offsets = counts + ncounts;             // ncounts
    int* bsums = offsets + ncounts;              // <= SCAN_BLK
    unsigned* sorted = (unsigned*)(bsums + SCAN_BLK);  // n_edges

    histA<<<nchunk, 1024, 0, stream>>>(dst, counts, nchunk, n_edges);

    int nb = (ncounts + SCAN_BLK - 1) / SCAN_BLK;      // ~59 (<=1024)
    bsum_kernel<<<nb, SCAN_BLK, 0, stream>>>(counts, bsums, ncounts);
    bscan_kernel<<<1, SCAN_BLK, 0, stream>>>(bsums, nb);
    offs_kernel<<<nb, SCAN_BLK, 0, stream>>>(counts, bsums, offsets, ncounts);

    scatterC<<<nchunk, 1024, 0, stream>>>(src, dst, offsets, sorted, nchunk, n_edges);

    size_t lds_bytes = (256 * RSTRIDE + 256) * sizeof(float);  // ~67.6 KB
    gatherD<<<NB, 1024, lds_bytes, stream>>>(feat, offsets, sorted, out, nchunk, n_edges);
}

// Round 7
// 87.140 us; speedup vs baseline: 6.4965x; 6.4965x over previous
//
#include <hip/hip_runtime.h>
#include <hip/hip_bf16.h>

#define N_NODES 100000
#define D 64
#define BSHIFT 8
#define NB 391            // ceil(100000 / 256) buckets of 256 nodes
#define CHUNK 8192
#define SCAN_BLK 1024

// ---------- A: per-(chunk,bucket) histogram via LDS atomics ----------
__global__ void histA(const int* __restrict__ dst, int* __restrict__ counts,
                      int nchunk, int n_edges) {
    __shared__ int h[NB];
    for (int i = threadIdx.x; i < NB; i += blockDim.x) h[i] = 0;
    __syncthreads();
    int c = blockIdx.x;
    int start = c * CHUNK, end = min(start + CHUNK, n_edges);
    for (int e = start + threadIdx.x; e < end; e += blockDim.x)
        atomicAdd(&h[dst[e] >> BSHIFT], 1);
    __syncthreads();
    for (int b = threadIdx.x; b < NB; b += blockDim.x)
        counts[b * nchunk + c] = h[b];   // bucket-major: scan order = final order
}

// ---------- B: 3-level exclusive scan ----------
__global__ void bsum_kernel(const int* __restrict__ counts, int* __restrict__ bsums,
                            int n) {
    __shared__ int s[SCAN_BLK];
    int i = blockIdx.x * SCAN_BLK + threadIdx.x;
    s[threadIdx.x] = (i < n) ? counts[i] : 0;
    __syncthreads();
    for (int off = SCAN_BLK / 2; off > 0; off >>= 1) {
        if (threadIdx.x < off) s[threadIdx.x] += s[threadIdx.x + off];
        __syncthreads();
    }
    if (threadIdx.x == 0) bsums[blockIdx.x] = s[0];
}
__global__ void bscan_kernel(int* __restrict__ bsums, int nb) {
    __shared__ int s[SCAN_BLK];
    int tid = threadIdx.x;
    s[tid] = (tid < nb) ? bsums[tid] : 0;
    __syncthreads();
    for (int off = 1; off < SCAN_BLK; off <<= 1) {
        int t = (tid >= off) ? s[tid - off] : 0;
        __syncthreads();
        s[tid] += t;
        __syncthreads();
    }
    if (tid < nb) bsums[tid] = (tid > 0) ? s[tid - 1] : 0;
}
__global__ void offs_kernel(const int* __restrict__ counts, const int* __restrict__ bsums,
                            int* __restrict__ offsets, int n) {
    __shared__ int s[SCAN_BLK];
    int tid = threadIdx.x;
    int i = blockIdx.x * SCAN_BLK + tid;
    int v = (i < n) ? counts[i] : 0;
    s[tid] = v;
    __syncthreads();
    for (int off = 1; off < SCAN_BLK; off <<= 1) {
        int t = (tid >= off) ? s[tid - off] : 0;
        __syncthreads();
        s[tid] += t;
        __syncthreads();
    }
    if (i < n) offsets[i] = s[tid] - v + bsums[blockIdx.x];
}

// ---------- C: bucket-sorted scatter via LDS cursors ----------
__global__ void scatterC(const int* __restrict__ src, const int* __restrict__ dst,
                         const int* __restrict__ base, unsigned* __restrict__ sorted,
                         int nchunk, int n_edges) {
    __shared__ int cur[NB];
    int c = blockIdx.x;
    for (int b = threadIdx.x; b < NB; b += blockDim.x) cur[b] = base[b * nchunk + c];
    __syncthreads();
    int start = c * CHUNK, end = min(start + CHUNK, n_edges);
    for (int e = start + threadIdx.x; e < end; e += blockDim.x) {
        int d = dst[e];
        int b = d >> BSHIFT;
        int r = atomicAdd(&cur[b], 1);
        sorted[r] = ((unsigned)(d & 255) << 17) | (unsigned)src[e];  // src < 2^17
    }
}

// ---------- D': per-bucket counting sort by node -> full dst order + CSR offsets ----------
__global__ void sortN(const unsigned* __restrict__ sorted, const int* __restrict__ base,
                      unsigned* __restrict__ sorted2, int* __restrict__ node_off,
                      int nchunk, int n_edges) {
    __shared__ int cnt[256];
    __shared__ int scan[256];
    __shared__ int cur[256];
    int b = blockIdx.x;
    int tid = threadIdx.x;
    int start = base[b * nchunk];
    int end = (b + 1 < NB) ? base[(b + 1) * nchunk] : n_edges;

    cnt[tid] = 0;
    __syncthreads();
    for (int e = start + tid; e < end; e += 256)
        atomicAdd(&cnt[(sorted[e] >> 17) & 255], 1);
    __syncthreads();

    // Hillis-Steele inclusive scan over 256 counts
    int v = cnt[tid];
    scan[tid] = v;
    __syncthreads();
    for (int off = 1; off < 256; off <<= 1) {
        int t = (tid >= off) ? scan[tid - off] : 0;
        __syncthreads();
        scan[tid] += t;
        __syncthreads();
    }
    int excl = scan[tid] - v;
    cur[tid] = excl;

    int node = (b << BSHIFT) + tid;
    if (node < N_NODES) node_off[node] = start + excl;
    if (b == NB - 1 && tid == 0) node_off[N_NODES] = n_edges;
    __syncthreads();

    for (int e = start + tid; e < end; e += 256) {
        unsigned p = sorted[e];
        int dl = (p >> 17) & 255;
        int pos = atomicAdd(&cur[dl], 1);
        sorted2[start + pos] = p & 0x1FFFF;   // src only
    }
}

// ---------- E: CSR gather, 4 nodes/wave, 16 lanes x float4, 4-deep unroll ----------
__global__ void gatherE(const float* __restrict__ feat,
                        const int* __restrict__ node_off,
                        const unsigned* __restrict__ sorted2,
                        float* __restrict__ out) {
    int wave = (blockIdx.x * blockDim.x + threadIdx.x) >> 6;
    int lane = threadIdx.x & 63;
    int group = lane >> 4;
    int gl = lane & 15;
    int node = wave * 4 + group;
    if (node >= N_NODES) return;

    int off = node_off[node];
    int end = node_off[node + 1];
    int deg = end - off;

    float4 acc = make_float4(0.f, 0.f, 0.f, 0.f);
    int e = off;
    for (; e + 4 <= end; e += 4) {
        int s0 = (int)sorted2[e];
        int s1 = (int)sorted2[e + 1];
        int s2 = (int)sorted2[e + 2];
        int s3 = (int)sorted2[e + 3];
        float4 v0 = *reinterpret_cast<const float4*>(&feat[(size_t)s0 * D + gl * 4]);
        float4 v1 = *reinterpret_cast<const float4*>(&feat[(size_t)s1 * D + gl * 4]);
        float4 v2 = *reinterpret_cast<const float4*>(&feat[(size_t)s2 * D + gl * 4]);
        float4 v3 = *reinterpret_cast<const float4*>(&feat[(size_t)s3 * D + gl * 4]);
        acc.x += v0.x + v1.x + v2.x + v3.x;
        acc.y += v0.y + v1.y + v2.y + v3.y;
        acc.z += v0.z + v1.z + v2.z + v3.z;
        acc.w += v0.w + v1.w + v2.w + v3.w;
    }
    for (; e < end; e++) {
        int s = (int)sorted2[e];
        float4 v = *reinterpret_cast<const float4*>(&feat[(size_t)s * D + gl * 4]);
        acc.x += v.x; acc.y += v.y; acc.z += v.z; acc.w += v.w;
    }

    float inv = (deg > 0) ? 1.0f / (float)deg : 0.0f;
    float4 o = make_float4(acc.x * inv, acc.y * inv, acc.z * inv, acc.w * inv);
    *reinterpret_cast<float4*>(&out[(size_t)node * D + gl * 4]) = o;
}

// ---------- fallback (atomic scatter) if ws too small ----------
__global__ void gcn_scatter(const float* __restrict__ feat, const int* __restrict__ src,
                            const int* __restrict__ dst, float* __restrict__ out,
                            float* __restrict__ deg, int n_edges) {
    long long gtid = (long long)blockIdx.x * blockDim.x + threadIdx.x;
    int edge = (int)(gtid >> 6);
    int lane = threadIdx.x & 63;
    if (edge >= n_edges) return;
    atomicAdd(&out[(long long)dst[edge] * D + lane],
              feat[(long long)src[edge] * D + lane]);
    if (lane == 0) atomicAdd(&deg[dst[edge]], 1.0f);
}
__global__ void gcn_finalize(float* __restrict__ out, const float* __restrict__ deg,
                             int total) {
    int i = blockIdx.x * blockDim.x + threadIdx.x;
    if (i >= total) return;
    float dg = deg[i >> 6];
    out[i] = (dg > 0.0f) ? out[i] / dg : 0.0f;
}

extern "C" void kernel_launch(void* const* d_in, const int* in_sizes, int n_in,
                              void* d_out, int out_size, void* d_ws, size_t ws_size,
                              hipStream_t stream) {
    const float* feat = (const float*)d_in[0];
    const int* src = (const int*)d_in[1];
    const int* dst = (const int*)d_in[2];
    float* out = (float*)d_out;
    int n_edges = in_sizes[1];

    int nchunk = (n_edges + CHUNK - 1) / CHUNK;
    int ncounts = NB * nchunk;
    size_t need = ((size_t)ncounts * 2 + SCAN_BLK + N_NODES + 1) * sizeof(int)
                + (size_t)n_edges * 2 * sizeof(unsigned);
    if (ws_size < need) {
        float* deg = (float*)d_ws;
        int total = N_NODES * D;
        hipMemsetAsync(out, 0, (size_t)total * sizeof(float), stream);
        hipMemsetAsync(deg, 0, (size_t)N_NODES * sizeof(float), stream);
        long long threads = (long long)n_edges * 64;
        int grid = (int)((threads + 255) / 256);
        gcn_scatter<<<grid, 256, 0, stream>>>(feat, src, dst, out, deg, n_edges);
        gcn_finalize<<<(total + 255) / 256, 256, 0, stream>>>(out, deg, total);
        return;
    }

    int* counts = (int*)d_ws;                          // ncounts
    int* offsets = counts + ncounts;                   // ncounts
    int* bsums = offsets + ncounts;                    // SCAN_BLK
    int* node_off = bsums + SCAN_BLK;                  // N_NODES + 1
    unsigned* sorted = (unsigned*)(node_off + N_NODES + 1);   // n_edges
    unsigned* sorted2 = sorted + n_edges;              // n_edges

    histA<<<nchunk, 1024, 0, stream>>>(dst, counts, nchunk, n_edges);

    int nb = (ncounts + SCAN_BLK - 1) / SCAN_BLK;      // <= 1024
    bsum_kernel<<<nb, SCAN_BLK, 0, stream>>>(counts, bsums, ncounts);
    bscan_kernel<<<1, SCAN_BLK, 0, stream>>>(bsums, nb);
    offs_kernel<<<nb, SCAN_BLK, 0, stream>>>(counts, bsums, offsets, ncounts);

    scatterC<<<nchunk, 1024, 0, stream>>>(src, dst, offsets, sorted, nchunk, n_edges);

    sortN<<<NB, 256, 0, stream>>>(sorted, offsets, sorted2, node_off, nchunk, n_edges);

    int nodes_per_block = (256 / 64) * 4;              // 16
    int ggrid = (N_NODES + nodes_per_block - 1) / nodes_per_block;
    gatherE<<<ggrid, 256, 0, stream>>>(feat, node_off, sorted2, out);
}

// Round 8
// 79.097 us; speedup vs baseline: 7.1571x; 1.1017x over previous
//
#include <hip/hip_runtime.h>
#include <hip/hip_bf16.h>

#define N_NODES 100000
#define D 64
#define BSHIFT 8
#define NB 391            // ceil(100000 / 256) buckets of 256 nodes
#define CHUNK 8192
#define SCAN_BLK 1024

typedef __attribute__((ext_vector_type(4))) _Float16 half4;

// ---------- feature f32 -> f16 (halves gather traffic; accum stays f32) ----------
__global__ void convF16(const float4* __restrict__ feat4, half4* __restrict__ feat16,
                        int n4) {
    int i = blockIdx.x * blockDim.x + threadIdx.x;
    if (i >= n4) return;
    float4 v = feat4[i];
    half4 h;
    h.x = (_Float16)v.x; h.y = (_Float16)v.y;
    h.z = (_Float16)v.z; h.w = (_Float16)v.w;
    feat16[i] = h;
}

// ---------- A: per-(chunk,bucket) histogram via LDS atomics ----------
__global__ void histA(const int* __restrict__ dst, int* __restrict__ counts,
                      int nchunk, int n_edges) {
    __shared__ int h[NB];
    for (int i = threadIdx.x; i < NB; i += blockDim.x) h[i] = 0;
    __syncthreads();
    int c = blockIdx.x;
    int start = c * CHUNK, end = min(start + CHUNK, n_edges);
    for (int e = start + threadIdx.x; e < end; e += blockDim.x)
        atomicAdd(&h[dst[e] >> BSHIFT], 1);
    __syncthreads();
    for (int b = threadIdx.x; b < NB; b += blockDim.x)
        counts[b * nchunk + c] = h[b];   // bucket-major: scan order = final order
}

// ---------- B: 3-level exclusive scan ----------
__global__ void bsum_kernel(const int* __restrict__ counts, int* __restrict__ bsums,
                            int n) {
    __shared__ int s[SCAN_BLK];
    int i = blockIdx.x * SCAN_BLK + threadIdx.x;
    s[threadIdx.x] = (i < n) ? counts[i] : 0;
    __syncthreads();
    for (int off = SCAN_BLK / 2; off > 0; off >>= 1) {
        if (threadIdx.x < off) s[threadIdx.x] += s[threadIdx.x + off];
        __syncthreads();
    }
    if (threadIdx.x == 0) bsums[blockIdx.x] = s[0];
}
__global__ void bscan_kernel(int* __restrict__ bsums, int nb) {
    __shared__ int s[SCAN_BLK];
    int tid = threadIdx.x;
    s[tid] = (tid < nb) ? bsums[tid] : 0;
    __syncthreads();
    for (int off = 1; off < SCAN_BLK; off <<= 1) {
        int t = (tid >= off) ? s[tid - off] : 0;
        __syncthreads();
        s[tid] += t;
        __syncthreads();
    }
    if (tid < nb) bsums[tid] = (tid > 0) ? s[tid - 1] : 0;
}
__global__ void offs_kernel(const int* __restrict__ counts, const int* __restrict__ bsums,
                            int* __restrict__ offsets, int n) {
    __shared__ int s[SCAN_BLK];
    int tid = threadIdx.x;
    int i = blockIdx.x * SCAN_BLK + tid;
    int v = (i < n) ? counts[i] : 0;
    s[tid] = v;
    __syncthreads();
    for (int off = 1; off < SCAN_BLK; off <<= 1) {
        int t = (tid >= off) ? s[tid - off] : 0;
        __syncthreads();
        s[tid] += t;
        __syncthreads();
    }
    if (i < n) offsets[i] = s[tid] - v + bsums[blockIdx.x];
}

// ---------- C: bucket-sorted scatter via LDS cursors ----------
__global__ void scatterC(const int* __restrict__ src, const int* __restrict__ dst,
                         const int* __restrict__ base, unsigned* __restrict__ sorted,
                         int nchunk, int n_edges) {
    __shared__ int cur[NB];
    int c = blockIdx.x;
    for (int b = threadIdx.x; b < NB; b += blockDim.x) cur[b] = base[b * nchunk + c];
    __syncthreads();
    int start = c * CHUNK, end = min(start + CHUNK, n_edges);
    for (int e = start + threadIdx.x; e < end; e += blockDim.x) {
        int d = dst[e];
        int b = d >> BSHIFT;
        int r = atomicAdd(&cur[b], 1);
        sorted[r] = ((unsigned)(d & 255) << 17) | (unsigned)src[e];  // src < 2^17
    }
}

// ---------- D': per-bucket counting sort by node -> full dst order + CSR offsets ----------
__global__ void sortN(const unsigned* __restrict__ sorted, const int* __restrict__ base,
                      unsigned* __restrict__ sorted2, int* __restrict__ node_off,
                      int nchunk, int n_edges) {
    __shared__ int cnt[256];
    __shared__ int scan[256];
    __shared__ int cur[256];
    int b = blockIdx.x;
    int tid = threadIdx.x;
    int start = base[b * nchunk];
    int end = (b + 1 < NB) ? base[(b + 1) * nchunk] : n_edges;

    cnt[tid] = 0;
    __syncthreads();
    for (int e = start + tid; e < end; e += 256)
        atomicAdd(&cnt[(sorted[e] >> 17) & 255], 1);
    __syncthreads();

    int v = cnt[tid];
    scan[tid] = v;
    __syncthreads();
    for (int off = 1; off < 256; off <<= 1) {
        int t = (tid >= off) ? scan[tid - off] : 0;
        __syncthreads();
        scan[tid] += t;
        __syncthreads();
    }
    int excl = scan[tid] - v;
    cur[tid] = excl;

    int node = (b << BSHIFT) + tid;
    if (node < N_NODES) node_off[node] = start + excl;
    if (b == NB - 1 && tid == 0) node_off[N_NODES] = n_edges;
    __syncthreads();

    for (int e = start + tid; e < end; e += 256) {
        unsigned p = sorted[e];
        int dl = (p >> 17) & 255;
        int pos = atomicAdd(&cur[dl], 1);
        sorted2[start + pos] = p & 0x1FFFF;   // src only
    }
}

// ---------- E(h): CSR gather from f16 table, 4 nodes/wave, 16 lanes x half4 ----------
__global__ void gatherE_h(const _Float16* __restrict__ feat16,
                          const int* __restrict__ node_off,
                          const unsigned* __restrict__ sorted2,
                          float* __restrict__ out) {
    int wave = (blockIdx.x * blockDim.x + threadIdx.x) >> 6;
    int lane = threadIdx.x & 63;
    int group = lane >> 4;
    int gl = lane & 15;
    int node = wave * 4 + group;
    if (node >= N_NODES) return;

    int off = node_off[node];
    int end = node_off[node + 1];
    int deg = end - off;

    float4 acc = make_float4(0.f, 0.f, 0.f, 0.f);
    int e = off;
    for (; e + 4 <= end; e += 4) {
        int s0 = (int)sorted2[e];
        int s1 = (int)sorted2[e + 1];
        int s2 = (int)sorted2[e + 2];
        int s3 = (int)sorted2[e + 3];
        half4 v0 = *reinterpret_cast<const half4*>(&feat16[(size_t)s0 * D + gl * 4]);
        half4 v1 = *reinterpret_cast<const half4*>(&feat16[(size_t)s1 * D + gl * 4]);
        half4 v2 = *reinterpret_cast<const half4*>(&feat16[(size_t)s2 * D + gl * 4]);
        half4 v3 = *reinterpret_cast<const half4*>(&feat16[(size_t)s3 * D + gl * 4]);
        acc.x += (float)v0.x + (float)v1.x + (float)v2.x + (float)v3.x;
        acc.y += (float)v0.y + (float)v1.y + (float)v2.y + (float)v3.y;
        acc.z += (float)v0.z + (float)v1.z + (float)v2.z + (float)v3.z;
        acc.w += (float)v0.w + (float)v1.w + (float)v2.w + (float)v3.w;
    }
    for (; e < end; e++) {
        int s = (int)sorted2[e];
        half4 v = *reinterpret_cast<const half4*>(&feat16[(size_t)s * D + gl * 4]);
        acc.x += (float)v.x; acc.y += (float)v.y;
        acc.z += (float)v.z; acc.w += (float)v.w;
    }

    float inv = (deg > 0) ? 1.0f / (float)deg : 0.0f;
    float4 o = make_float4(acc.x * inv, acc.y * inv, acc.z * inv, acc.w * inv);
    *reinterpret_cast<float4*>(&out[(size_t)node * D + gl * 4]) = o;
}

// ---------- E(f32): R7 gather, used when ws can't hold the f16 table ----------
__global__ void gatherE(const float* __restrict__ feat,
                        const int* __restrict__ node_off,
                        const unsigned* __restrict__ sorted2,
                        float* __restrict__ out) {
    int wave = (blockIdx.x * blockDim.x + threadIdx.x) >> 6;
    int lane = threadIdx.x & 63;
    int group = lane >> 4;
    int gl = lane & 15;
    int node = wave * 4 + group;
    if (node >= N_NODES) return;

    int off = node_off[node];
    int end = node_off[node + 1];
    int deg = end - off;

    float4 acc = make_float4(0.f, 0.f, 0.f, 0.f);
    int e = off;
    for (; e + 4 <= end; e += 4) {
        int s0 = (int)sorted2[e];
        int s1 = (int)sorted2[e + 1];
        int s2 = (int)sorted2[e + 2];
        int s3 = (int)sorted2[e + 3];
        float4 v0 = *reinterpret_cast<const float4*>(&feat[(size_t)s0 * D + gl * 4]);
        float4 v1 = *reinterpret_cast<const float4*>(&feat[(size_t)s1 * D + gl * 4]);
        float4 v2 = *reinterpret_cast<const float4*>(&feat[(size_t)s2 * D + gl * 4]);
        float4 v3 = *reinterpret_cast<const float4*>(&feat[(size_t)s3 * D + gl * 4]);
        acc.x += v0.x + v1.x + v2.x + v3.x;
        acc.y += v0.y + v1.y + v2.y + v3.y;
        acc.z += v0.z + v1.z + v2.z + v3.z;
        acc.w += v0.w + v1.w + v2.w + v3.w;
    }
    for (; e < end; e++) {
        int s = (int)sorted2[e];
        float4 v = *reinterpret_cast<const float4*>(&feat[(size_t)s * D + gl * 4]);
        acc.x += v.x; acc.y += v.y; acc.z += v.z; acc.w += v.w;
    }

    float inv = (deg > 0) ? 1.0f / (float)deg : 0.0f;
    float4 o = make_float4(acc.x * inv, acc.y * inv, acc.z * inv, acc.w * inv);
    *reinterpret_cast<float4*>(&out[(size_t)node * D + gl * 4]) = o;
}

// ---------- fallback (atomic scatter) if ws too small ----------
__global__ void gcn_scatter(const float* __restrict__ feat, const int* __restrict__ src,
                            const int* __restrict__ dst, float* __restrict__ out,
                            float* __restrict__ deg, int n_edges) {
    long long gtid = (long long)blockIdx.x * blockDim.x + threadIdx.x;
    int edge = (int)(gtid >> 6);
    int lane = threadIdx.x & 63;
    if (edge >= n_edges) return;
    atomicAdd(&out[(long long)dst[edge] * D + lane],
              feat[(long long)src[edge] * D + lane]);
    if (lane == 0) atomicAdd(&deg[dst[edge]], 1.0f);
}
__global__ void gcn_finalize(float* __restrict__ out, const float* __restrict__ deg,
                             int total) {
    int i = blockIdx.x * blockDim.x + threadIdx.x;
    if (i >= total) return;
    float dg = deg[i >> 6];
    out[i] = (dg > 0.0f) ? out[i] / dg : 0.0f;
}

extern "C" void kernel_launch(void* const* d_in, const int* in_sizes, int n_in,
                              void* d_out, int out_size, void* d_ws, size_t ws_size,
                              hipStream_t stream) {
    const float* feat = (const float*)d_in[0];
    const int* src = (const int*)d_in[1];
    const int* dst = (const int*)d_in[2];
    float* out = (float*)d_out;
    int n_edges = in_sizes[1];

    int nchunk = (n_edges + CHUNK - 1) / CHUNK;
    int ncounts = NB * nchunk;
    size_t base_need = ((size_t)ncounts * 2 + SCAN_BLK + N_NODES + 1) * sizeof(int)
                     + (size_t)n_edges * 2 * sizeof(unsigned);
    size_t f16_bytes = (size_t)N_NODES * D * sizeof(_Float16);   // 12.8 MB
    bool use_f16 = (ws_size >= base_need + f16_bytes);

    if (ws_size < base_need) {
        float* deg = (float*)d_ws;
        int total = N_NODES * D;
        hipMemsetAsync(out, 0, (size_t)total * sizeof(float), stream);
        hipMemsetAsync(deg, 0, (size_t)N_NODES * sizeof(float), stream);
        long long threads = (long long)n_edges * 64;
        int grid = (int)((threads + 255) / 256);
        gcn_scatter<<<grid, 256, 0, stream>>>(feat, src, dst, out, deg, n_edges);
        gcn_finalize<<<(total + 255) / 256, 256, 0, stream>>>(out, deg, total);
        return;
    }

    char* wp = (char*)d_ws;
    _Float16* feat16 = nullptr;
    if (use_f16) { feat16 = (_Float16*)wp; wp += f16_bytes; }
    int* counts = (int*)wp;                            // ncounts
    int* offsets = counts + ncounts;                   // ncounts
    int* bsums = offsets + ncounts;                    // SCAN_BLK
    int* node_off = bsums + SCAN_BLK;                  // N_NODES + 1
    unsigned* sorted = (unsigned*)(node_off + N_NODES + 1);   // n_edges
    unsigned* sorted2 = sorted + n_edges;              // n_edges

    if (use_f16) {
        int n4 = N_NODES * D / 4;                      // 1.6M float4s
        convF16<<<(n4 + 255) / 256, 256, 0, stream>>>(
            (const float4*)feat, (half4*)feat16, n4);
    }

    histA<<<nchunk, 1024, 0, stream>>>(dst, counts, nchunk, n_edges);

    int nb = (ncounts + SCAN_BLK - 1) / SCAN_BLK;      // <= 1024
    bsum_kernel<<<nb, SCAN_BLK, 0, stream>>>(counts, bsums, ncounts);
    bscan_kernel<<<1, SCAN_BLK, 0, stream>>>(bsums, nb);
    offs_kernel<<<nb, SCAN_BLK, 0, stream>>>(counts, bsums, offsets, ncounts);

    scatterC<<<nchunk, 1024, 0, stream>>>(src, dst, offsets, sorted, nchunk, n_edges);

    sortN<<<NB, 256, 0, stream>>>(sorted, offsets, sorted2, node_off, nchunk, n_edges);

    int nodes_per_block = (256 / 64) * 4;              // 16
    int ggrid = (N_NODES + nodes_per_block - 1) / nodes_per_block;
    if (use_f16)
        gatherE_h<<<ggrid, 256, 0, stream>>>(feat16, node_off, sorted2, out);
    else
        gatherE<<<ggrid, 256, 0, stream>>>(feat, node_off, sorted2, out);
}

// Round 9
// 61.371 us; speedup vs baseline: 9.2243x; 1.2888x over previous
//
#include <hip/hip_runtime.h>
#include <hip/hip_bf16.h>

#define N_NODES 100000
#define D 64
#define BSHIFT 8
#define NB 391            // ceil(100000/256) buckets of 256 nodes
#define CHUNK 8192
#define LDS_CAP 4096      // max edges per bucket held in LDS (mean 3200, sd ~56)

typedef __attribute__((ext_vector_type(4))) _Float16 half4;

// ---------- K1: feature f32->f16 conversion + per-(chunk,bucket) histogram ----------
__global__ void convhist(const float4* __restrict__ feat4, half4* __restrict__ feat16,
                         int n4, const int* __restrict__ dst, int* __restrict__ counts,
                         int nchunk, int n_edges) {
    // conv: grid-stride over the whole table
    for (int i = blockIdx.x * blockDim.x + threadIdx.x; i < n4;
         i += gridDim.x * blockDim.x) {
        float4 v = feat4[i];
        half4 h;
        h.x = (_Float16)v.x; h.y = (_Float16)v.y;
        h.z = (_Float16)v.z; h.w = (_Float16)v.w;
        feat16[i] = h;
    }
    // hist: one chunk per block (blocks >= nchunk skip)
    __shared__ int h[NB];
    int c = blockIdx.x;
    if (c >= nchunk) return;
    for (int i = threadIdx.x; i < NB; i += blockDim.x) h[i] = 0;
    __syncthreads();
    int s = c * CHUNK, e = min(s + CHUNK, n_edges);
    for (int i = s + threadIdx.x; i < e; i += blockDim.x)
        atomicAdd(&h[dst[i] >> BSHIFT], 1);
    __syncthreads();
    for (int b = threadIdx.x; b < NB; b += blockDim.x)
        counts[(size_t)b * nchunk + c] = h[b];   // bucket-major
}

// ---------- K2: per-bucket exclusive scan over chunk counts (tiled, carry) ----------
__global__ void scanB(int* __restrict__ counts, int* __restrict__ totals, int nchunk) {
    __shared__ int s[256];
    int b = blockIdx.x;
    int tid = threadIdx.x;      // 256 threads
    int carry = 0;
    int* row = counts + (size_t)b * nchunk;
    for (int t0 = 0; t0 < nchunk; t0 += 256) {
        int i = t0 + tid;
        int v = (i < nchunk) ? row[i] : 0;
        s[tid] = v;
        __syncthreads();
        for (int off = 1; off < 256; off <<= 1) {
            int t = (tid >= off) ? s[tid - off] : 0;
            __syncthreads();
            s[tid] += t;
            __syncthreads();
        }
        if (i < nchunk) row[i] = s[tid] - v + carry;   // exclusive within bucket
        carry += s[255];
        __syncthreads();
    }
    if (tid == 0) totals[b] = carry;
}

// ---------- K3: scatter to bucket order; base computed by in-block totals scan ----------
__global__ void scatter2(const int* __restrict__ src, const int* __restrict__ dst,
                         const int* __restrict__ counts, const int* __restrict__ totals,
                         unsigned* __restrict__ sorted, int nchunk, int n_edges) {
    __shared__ int t0[512], tv[512];
    __shared__ int cur[NB];
    int tid = threadIdx.x;      // 1024
    if (tid < 512) { int v = (tid < NB) ? totals[tid] : 0; t0[tid] = v; tv[tid] = v; }
    __syncthreads();
    for (int off = 1; off < 512; off <<= 1) {
        int t = 0;
        if (tid < 512 && tid >= off) t = t0[tid - off];
        __syncthreads();
        if (tid < 512) t0[tid] += t;
        __syncthreads();
    }
    int c = blockIdx.x;
    for (int b = tid; b < NB; b += blockDim.x)
        cur[b] = (t0[b] - tv[b]) + counts[(size_t)b * nchunk + c];
    __syncthreads();
    int s = c * CHUNK, e = min(s + CHUNK, n_edges);
    for (int i = s + tid; i < e; i += blockDim.x) {
        int d = dst[i];
        int b = d >> BSHIFT;
        int r = atomicAdd(&cur[b], 1);
        sorted[r] = ((unsigned)(d & 255) << 17) | (unsigned)src[i];  // src < 2^17
    }
}

// ---------- K4: per-bucket counting sort into LDS + fp16 gather ----------
__global__ void sortGather(const _Float16* __restrict__ feat16,
                           const unsigned* __restrict__ sorted,
                           const int* __restrict__ totals,
                           unsigned* __restrict__ sorted2,   // spill path only
                           float* __restrict__ out) {
    __shared__ int t0[512], tv[512];
    __shared__ int cnt[256];
    __shared__ int noff[257];
    __shared__ int cur[256];
    __shared__ unsigned lsrc[LDS_CAP];
    int tid = threadIdx.x;      // 1024
    int b = blockIdx.x;

    // bucket base via totals scan
    if (tid < 512) { int v = (tid < NB) ? totals[tid] : 0; t0[tid] = v; tv[tid] = v; }
    __syncthreads();
    for (int off = 1; off < 512; off <<= 1) {
        int t = 0;
        if (tid < 512 && tid >= off) t = t0[tid - off];
        __syncthreads();
        if (tid < 512) t0[tid] += t;
        __syncthreads();
    }
    int start = t0[b] - tv[b];
    int cntb = tv[b];
    bool big = (cntb > LDS_CAP);

    // count node-local ids
    if (tid < 256) cnt[tid] = 0;
    __syncthreads();
    for (int i = tid; i < cntb; i += 1024)
        atomicAdd(&cnt[(sorted[start + i] >> 17) & 255], 1);
    __syncthreads();

    // scan 256 counts (reuse t0)
    if (tid < 256) t0[tid] = cnt[tid];
    __syncthreads();
    for (int off = 1; off < 256; off <<= 1) {
        int t = 0;
        if (tid < 256 && tid >= off) t = t0[tid - off];
        __syncthreads();
        if (tid < 256) t0[tid] += t;
        __syncthreads();
    }
    if (tid < 256) { noff[tid] = t0[tid] - cnt[tid]; cur[tid] = noff[tid]; }
    if (tid == 0) noff[256] = cntb;
    __syncthreads();

    // place into LDS (or global spill for oversized bucket)
    if (!big) {
        for (int i = tid; i < cntb; i += 1024) {
            unsigned p = sorted[start + i];
            int pos = atomicAdd(&cur[(p >> 17) & 255], 1);
            lsrc[pos] = p & 0x1FFFF;
        }
    } else {
        for (int i = tid; i < cntb; i += 1024) {
            unsigned p = sorted[start + i];
            int pos = atomicAdd(&cur[(p >> 17) & 255], 1);
            sorted2[start + pos] = p & 0x1FFFF;
        }
    }
    __syncthreads();

    // gather: 64 groups of 16 lanes; 4 nodes serial per group
    int g = tid >> 4, gl = tid & 15;
    for (int n = g; n < 256; n += 64) {
        int node = (b << BSHIFT) + n;
        if (node >= N_NODES) break;
        int off = noff[n], endn = noff[n + 1];
        int deg = endn - off;
        float4 acc = make_float4(0.f, 0.f, 0.f, 0.f);
        int e = off;
        if (!big) {
            for (; e + 4 <= endn; e += 4) {
                int s0 = lsrc[e], s1 = lsrc[e + 1], s2 = lsrc[e + 2], s3 = lsrc[e + 3];
                half4 v0 = *reinterpret_cast<const half4*>(&feat16[(size_t)s0 * D + gl * 4]);
                half4 v1 = *reinterpret_cast<const half4*>(&feat16[(size_t)s1 * D + gl * 4]);
                half4 v2 = *reinterpret_cast<const half4*>(&feat16[(size_t)s2 * D + gl * 4]);
                half4 v3 = *reinterpret_cast<const half4*>(&feat16[(size_t)s3 * D + gl * 4]);
                acc.x += (float)v0.x + (float)v1.x + (float)v2.x + (float)v3.x;
                acc.y += (float)v0.y + (float)v1.y + (float)v2.y + (float)v3.y;
                acc.z += (float)v0.z + (float)v1.z + (float)v2.z + (float)v3.z;
                acc.w += (float)v0.w + (float)v1.w + (float)v2.w + (float)v3.w;
            }
            for (; e < endn; e++) {
                int s = lsrc[e];
                half4 v = *reinterpret_cast<const half4*>(&feat16[(size_t)s * D + gl * 4]);
                acc.x += (float)v.x; acc.y += (float)v.y;
                acc.z += (float)v.z; acc.w += (float)v.w;
            }
        } else {
            for (; e < endn; e++) {
                int s = (int)sorted2[start + e];
                half4 v = *reinterpret_cast<const half4*>(&feat16[(size_t)s * D + gl * 4]);
                acc.x += (float)v.x; acc.y += (float)v.y;
                acc.z += (float)v.z; acc.w += (float)v.w;
            }
        }
        float inv = (deg > 0) ? 1.0f / (float)deg : 0.0f;
        float4 o = make_float4(acc.x * inv, acc.y * inv, acc.z * inv, acc.w * inv);
        *reinterpret_cast<float4*>(&out[(size_t)node * D + gl * 4]) = o;
    }
}

// ---------- fallback (atomic scatter) if ws too small ----------
__global__ void gcn_scatter(const float* __restrict__ feat, const int* __restrict__ src,
                            const int* __restrict__ dst, float* __restrict__ out,
                            float* __restrict__ deg, int n_edges) {
    long long gtid = (long long)blockIdx.x * blockDim.x + threadIdx.x;
    int edge = (int)(gtid >> 6);
    int lane = threadIdx.x & 63;
    if (edge >= n_edges) return;
    atomicAdd(&out[(long long)dst[edge] * D + lane],
              feat[(long long)src[edge] * D + lane]);
    if (lane == 0) atomicAdd(&deg[dst[edge]], 1.0f);
}
__global__ void gcn_finalize(float* __restrict__ out, const float* __restrict__ deg,
                             int total) {
    int i = blockIdx.x * blockDim.x + threadIdx.x;
    if (i >= total) return;
    float dg = deg[i >> 6];
    out[i] = (dg > 0.0f) ? out[i] / dg : 0.0f;
}

extern "C" void kernel_launch(void* const* d_in, const int* in_sizes, int n_in,
                              void* d_out, int out_size, void* d_ws, size_t ws_size,
                              hipStream_t stream) {
    const float* feat = (const float*)d_in[0];
    const int* src = (const int*)d_in[1];
    const int* dst = (const int*)d_in[2];
    float* out = (float*)d_out;
    int n_edges = in_sizes[1];

    int nchunk = (n_edges + CHUNK - 1) / CHUNK;
    size_t ncounts = (size_t)NB * nchunk;
    size_t f16_bytes = (size_t)N_NODES * D * sizeof(_Float16);   // 12.8 MB
    size_t need = f16_bytes + (ncounts + NB) * sizeof(int)
                + (size_t)n_edges * 2 * sizeof(unsigned);

    if (ws_size < need) {
        float* deg = (float*)d_ws;
        int total = N_NODES * D;
        hipMemsetAsync(out, 0, (size_t)total * sizeof(float), stream);
        hipMemsetAsync(deg, 0, (size_t)N_NODES * sizeof(float), stream);
        long long threads = (long long)n_edges * 64;
        int grid = (int)((threads + 255) / 256);
        gcn_scatter<<<grid, 256, 0, stream>>>(feat, src, dst, out, deg, n_edges);
        gcn_finalize<<<(total + 255) / 256, 256, 0, stream>>>(out, deg, total);
        return;
    }

    char* wp = (char*)d_ws;
    _Float16* feat16 = (_Float16*)wp;            wp += f16_bytes;
    int* counts = (int*)wp;                      wp += ncounts * sizeof(int);
    int* totals = (int*)wp;                      wp += (size_t)NB * sizeof(int);
    unsigned* sorted = (unsigned*)wp;            wp += (size_t)n_edges * sizeof(unsigned);
    unsigned* sorted2 = (unsigned*)wp;           // spill path only

    int n4 = N_NODES * D / 4;
    int chgrid = (nchunk > 256) ? nchunk : 256;
    convhist<<<chgrid, 1024, 0, stream>>>((const float4*)feat, (half4*)feat16, n4,
                                          dst, counts, nchunk, n_edges);
    scanB<<<NB, 256, 0, stream>>>(counts, totals, nchunk);
    scatter2<<<nchunk, 1024, 0, stream>>>(src, dst, counts, totals, sorted,
                                          nchunk, n_edges);
    sortGather<<<NB, 1024, 0, stream>>>(feat16, sorted, totals, sorted2, out);
}